// Round 17
// baseline (1344.241 us; speedup 1.0000x reference)
//
#include <hip/hip_runtime.h>
#include <math.h>

// NeuroSAT, MI355X. Round 17: r14 + broadcast-VMEM weights, COMPILER-scheduled.
//  - r15/r16 lesson: hand-rolled asm double-buffering of broadcast loads
//    either doesn't compile ("+v" float4) or faults (r16 core dump). hipcc
//    already emits counted vmcnt waits + hoists independent global loads
//    (guide G7/m97), so a plain unrolled C++ loop gets the same pipeline
//    safely.
//  - Weights: lane-invariant float4 global loads (1 L1 tx broadcast, VMEM
//    pipe; no LDS traffic, no SMEM full-drain). Rows: conflict-free
//    transposed LDS tile (as r13/r14).
//  - FMA order identical to r13/r14 -> absmax must be exactly 0.01269531.
//  - All else identical to r14 (2 dispatches/step, 512thr/8-wave, lane=row,
//    folded affine MLPs, padded CSR, merged setup).

#define NV2_   800
#define NC_    440
#define KK_    12
#define NPG_   1240
#define NLIT_  12800
#define NCLS_  7040
#define NE_    84480
#define NN_    19840
#define STEPS_ 23

__device__ __forceinline__ float sigmf(float x) { return 1.0f / (1.0f + __expf(-x)); }
__device__ __forceinline__ float tanhf_(float x) { return 1.0f - 2.0f / (__expf(2.0f * x) + 1.0f); }

// ---------------- setup kernels ----------------

__global__ __launch_bounds__(64) void collapseT_k(
    const float* lm1, const float* lm1b, const float* lm2, const float* lm2b,
    const float* cm1, const float* cm1b, const float* cm2, const float* cm2b,
    float* T, float* ub)
{
    int r = blockIdx.x >> 6, i = blockIdx.x & 63, j = threadIdx.x;
    const float* w1 = r ? cm1 : lm1; const float* b1 = r ? cm1b : lm1b;
    const float* w2 = r ? cm2 : lm2; const float* b2 = r ? cm2b : lm2b;
    float s = 0.f;
    for (int k = 0; k < 64; ++k) s += w1[i * 64 + k] * w2[k * 64 + j];
    T[r * 4096 + i * 64 + j] = s;
    if (i == 0) {
        float s2 = 0.f;
        for (int k = 0; k < 64; ++k) s2 += b1[k] * w2[k * 64 + j];
        ub[r * 64 + j] = s2 + b2[j];
    }
}

__global__ __launch_bounds__(64) void collapseW_k(
    const float* lm3, const float* lm3b, const float* cm3, const float* cm3b,
    const float* T, const float* ub,
    float* Wl, float* bl, float* Wc, float* bc,
    const float* lv1, const float* lv1b, const float* lv2, const float* lv2b,
    const float* lv3, const float* lv3b, float* Wv, float* bv)
{
    int t = threadIdx.x;
    if (blockIdx.x < 128) {
        int r = blockIdx.x >> 6, i = blockIdx.x & 63, j = t;
        const float* w3 = r ? cm3 : lm3; const float* b3 = r ? cm3b : lm3b;
        float* W = r ? Wc : Wl; float* bb = r ? bc : bl;
        float s = 0.f;
        for (int k = 0; k < 64; ++k) s += T[r * 4096 + i * 64 + k] * w3[k * 64 + j];
        W[i * 64 + j] = s;
        if (i == 0) {
            float s2 = 0.f;
            for (int k = 0; k < 64; ++k) s2 += ub[r * 64 + k] * w3[k * 64 + j];
            bb[j] = s2 + b3[j];
        }
    } else {
        __shared__ float t3[64];
        __shared__ float ub2[64];
        float s = 0.f;
        for (int j = 0; j < 64; ++j) s += lv2[t * 64 + j] * lv3[j];
        t3[t] = s;
        float s2 = 0.f;
        for (int k = 0; k < 64; ++k) s2 += lv1b[k] * lv2[k * 64 + t];
        ub2[t] = s2 + lv2b[t];
        __syncthreads();
        float s3 = 0.f;
        for (int k = 0; k < 64; ++k) s3 += lv1[t * 64 + k] * t3[k];
        Wv[t] = s3;
        if (t == 0) {
            float v = 0.f;
            for (int j = 0; j < 64; ++j) v += ub2[j] * lv3[j];
            bv[0] = v + lv3b[0];
        }
    }
}

__global__ __launch_bounds__(256) void fold2_k(
    const float* Wl, const float* bl, const float* Wc, const float* bc,
    const float* lwih, const float* lbih, const float* lbhh,
    const float* cwih, const float* cbih, const float* cbhh,
    float* Wfl, float* bfl, float* Bl, float* Wfc, float* Bc)
{
    int t = blockIdx.x >> 6, i = blockIdx.x & 63, j = threadIdx.x;
    if (t == 0) {
        float s = 0.f;
        for (int m = 0; m < 64; ++m) s += Wc[i * 64 + m] * lwih[(64 + m) * 256 + j];
        Wfl[i * 256 + j] = s;
        if (i == 0) {
            float s2 = 0.f;
            for (int m = 0; m < 64; ++m) s2 += bc[m] * lwih[(64 + m) * 256 + j];
            bfl[j] = s2;
            Bl[j] = lbih[j] + lbhh[j];
        }
    } else {
        float s = 0.f;
        for (int m = 0; m < 64; ++m) s += Wl[i * 64 + m] * cwih[m * 256 + j];
        Wfc[i * 256 + j] = s;
        if (i == 0) {
            float s2 = 0.f;
            for (int m = 0; m < 64; ++m) s2 += bl[m] * cwih[m * 256 + j];
            Bc[j] = cbih[j] + cbhh[j] + 13.f * s2;
        }
    }
}

// 5 matrices x 16 hc: [64][256] -> [hc][k][u4*4+g]
struct WT5 { const float* src[5]; float* dst[5]; };
__global__ __launch_bounds__(1024) void wtransAll_k(WT5 a)
{
    int m = blockIdx.x >> 4;
    int hc = blockIdx.x & 15;
    int half = hc >> 3, chunk = hc & 7;
    int t = threadIdx.x;
    int k = t >> 4, u4 = (t >> 2) & 3, g = t & 3;
    a.dst[m][(hc * 64 + k) * 16 + u4 * 4 + g] =
        a.src[m][k * 256 + g * 64 + half * 32 + chunk * 4 + u4];
}

__global__ __launch_bounds__(256) void init_k(
    const float* x, const float* liw, const float* lib, const float* ciw, const float* cib,
    float* out0, float* outc, float* chA, float* chB)
{
    int t = blockIdx.x * 256 + threadIdx.x;
    if (t < 64) {
        chA[(size_t)NCLS_ * 64 + t] = 0.f;
        chB[(size_t)NCLS_ * 64 + t] = 0.f;
    }
    if (t >= NN_ * 64) return;
    int node = t >> 6, j = t & 63;
    int b = node / NPG_;
    int i = node - b * NPG_;
    float x0 = x[node * 2 + 0], x1 = x[node * 2 + 1];
    if (i < NV2_) {
        int sp = (i < 400) ? 2 * i : 2 * (i - 400) + 1;
        out0[(size_t)(b * NV2_ + sp) * 64 + j] = x0 * liw[j] + x1 * liw[64 + j] + lib[j];
    } else {
        outc[(size_t)(b * NC_ + (i - NV2_)) * 64 + j] = x0 * ciw[j] + x1 * ciw[64 + j] + cib[j];
    }
}

__global__ __launch_bounds__(256) void econv_k(const int* ei, int* llits, int* cnt)
{
    int e = blockIdx.x * 256 + threadIdx.x;
    if (e >= NE_) return;
    int g = ei[e];
    int b = g / NPG_;
    int i = g - b * NPG_;
    int sp = (i < 400) ? 2 * i : 2 * (i - 400) + 1;
    int L = b * NV2_ + sp;
    llits[e] = L;
    atomicAdd(cnt + L, 1);
}

__global__ __launch_bounds__(1024) void scan_k(const int* cnt, int* rowptr, int* cursor)
{
    __shared__ int sums[1024];
    int t = threadIdx.x;
    int i0 = t * 13;
    int i1 = i0 + 13; if (i1 > NLIT_) i1 = NLIT_; if (i0 > NLIT_) i0 = NLIT_;
    int s = 0;
    for (int i = i0; i < i1; ++i) s += (cnt[i] + 7) & ~7;
    sums[t] = s;
    __syncthreads();
    for (int off = 1; off < 1024; off <<= 1) {
        int v = (t >= off) ? sums[t - off] : 0;
        __syncthreads();
        sums[t] += v;
        __syncthreads();
    }
    int run = sums[t] - s;
    for (int i = i0; i < i1; ++i) {
        rowptr[i] = run; cursor[i] = run;
        run += (cnt[i] + 7) & ~7;
    }
    if (t == 1023) rowptr[NLIT_] = sums[1023];
}

__global__ __launch_bounds__(256) void fill_k(const int* llits, int* cursor, int* col)
{
    int e = blockIdx.x * 256 + threadIdx.x;
    if (e >= NE_) return;
    int pos = atomicAdd(cursor + llits[e], 1);
    col[pos] = e / KK_;
}

__global__ __launch_bounds__(256) void pad_k(const int* cnt, const int* rowptr, int* col)
{
    int i = blockIdx.x * 256 + threadIdx.x;
    if (i >= NLIT_) return;
    for (int e = rowptr[i] + cnt[i]; e < rowptr[i + 1]; ++e) col[e] = NCLS_;
}

// ---------------- broadcast-VMEM weight gemm (compiler-pipelined) ----------------

#define FMA16(rv, a,b,c,d) \
    acc[0]  = fmaf(rv, a.x, acc[0]);  acc[1]  = fmaf(rv, a.y, acc[1]);  \
    acc[2]  = fmaf(rv, a.z, acc[2]);  acc[3]  = fmaf(rv, a.w, acc[3]);  \
    acc[4]  = fmaf(rv, b.x, acc[4]);  acc[5]  = fmaf(rv, b.y, acc[5]);  \
    acc[6]  = fmaf(rv, b.z, acc[6]);  acc[7]  = fmaf(rv, b.w, acc[7]);  \
    acc[8]  = fmaf(rv, c.x, acc[8]);  acc[9]  = fmaf(rv, c.y, acc[9]);  \
    acc[10] = fmaf(rv, c.z, acc[10]); acc[11] = fmaf(rv, c.w, acc[11]); \
    acc[12] = fmaf(rv, d.x, acc[12]); acc[13] = fmaf(rv, d.y, acc[13]); \
    acc[14] = fmaf(rv, d.z, acc[14]); acc[15] = fmaf(rv, d.w, acc[15]);

// acc[u4*4+g] += sum_k Ls[k*65 + (lane^rx)] * wb[k*16 + u4*4+g]
// Weight addr is lane-invariant: each float4 load is ONE broadcast L1 tx on
// the VMEM pipe. unroll 4 lets the compiler hoist loads + emit counted vmcnt.
__device__ __forceinline__ void gemmV(const float* __restrict__ Ls, int rx,
                                      const float* __restrict__ wb, float* acc)
{
    const int r = (threadIdx.x & 63) ^ rx;
    const float4* __restrict__ wp = (const float4*)wb;
#pragma unroll 4
    for (int k = 0; k < 64; ++k) {
        float4 w0 = wp[k * 4 + 0];
        float4 w1 = wp[k * 4 + 1];
        float4 w2 = wp[k * 4 + 2];
        float4 w3 = wp[k * 4 + 3];
        float rf = Ls[k * 65 + r];
        FMA16(rf, w0, w1, w2, w3);
    }
}

__device__ __forceinline__ void cellu(const float* a, float* c, float* h)
{
    float iv = sigmf(a[0]);
    float fv = sigmf(a[1]);
    float gv = tanhf_(a[2]);
    float ov = sigmf(a[3]);
    float c2 = fv * (*c) + iv * gv;
    *c = c2;
    *h = ov * tanhf_(c2);
}

// ---------------- per-step kernels (512 thr, 8 waves, lane=row, 64 rows) ----------------

// clause: 220 blocks (110 rowgrps x 2 halves)
__global__ __launch_bounds__(512, 4) void clause_step_k(
    const float* __restrict__ out_cur, const float* __restrict__ outc0,
    float* __restrict__ ch_cur, const float* __restrict__ ch_prev, float* __restrict__ ccg,
    const int* __restrict__ llits,
    const float* __restrict__ wfcT, const float* __restrict__ cwhhT,
    const float* __restrict__ Bc, int step)
{
    __shared__ float bufT[65 * 64];          // [k][r]
    __shared__ float chT[65 * 64];
    const int tid = threadIdx.x;
    const int lane = tid & 63;
    const int wv = tid >> 6;                 // 0..7 chunk
    const int half = blockIdx.x & 1;
    const int Cb = (blockIdx.x >> 1) * 64;
    const int chunk = __builtin_amdgcn_readfirstlane(wv);
    const int hc = half * 8 + chunk;

    for (int i = 0; i < 8; ++i) {
        int srow = wv * 8 + i;
        int c = Cb + srow;
        float v;
        if (step) {
            float ch0 = ch_prev[(size_t)c * 64 + lane];
            chT[lane * 65 + srow] = ch0;
            v = ch0;
        } else {
            v = outc0[(size_t)c * 64 + lane];
        }
        const int* lp = llits + c * KK_;
        float t0 = out_cur[(size_t)lp[0] * 64 + lane];
        float t1 = out_cur[(size_t)lp[1] * 64 + lane];
        float t2 = out_cur[(size_t)lp[2] * 64 + lane];
        float t3 = out_cur[(size_t)lp[3] * 64 + lane];
        float t4 = out_cur[(size_t)lp[4] * 64 + lane];
        float t5 = out_cur[(size_t)lp[5] * 64 + lane];
        float t6 = out_cur[(size_t)lp[6] * 64 + lane];
        float t7 = out_cur[(size_t)lp[7] * 64 + lane];
        float t8 = out_cur[(size_t)lp[8] * 64 + lane];
        float t9 = out_cur[(size_t)lp[9] * 64 + lane];
        float ta = out_cur[(size_t)lp[10] * 64 + lane];
        float tb = out_cur[(size_t)lp[11] * 64 + lane];
        v += t0 + t1 + t2 + t3 + t4 + t5 + t6 + t7 + t8 + t9 + ta + tb;
        bufT[lane * 65 + srow] = v;
    }
    __syncthreads();

    float acc[16];
    if (step) {
#pragma unroll
        for (int i = 0; i < 16; ++i) acc[i] = 0.f;
        gemmV(chT, 0, cwhhT + hc * 1024, acc);       // ch(s-1) @ whh
#pragma unroll
        for (int u4 = 0; u4 < 4; ++u4)
#pragma unroll
            for (int g = 0; g < 4; ++g)
                acc[u4 * 4 + g] += Bc[g * 64 + half * 32 + chunk * 4 + u4];
    } else {
#pragma unroll
        for (int u4 = 0; u4 < 4; ++u4)
#pragma unroll
            for (int g = 0; g < 4; ++g)
                acc[u4 * 4 + g] = Bc[g * 64 + half * 32 + chunk * 4 + u4];
    }
    gemmV(bufT, 0, wfcT + hc * 1024, acc);           // folded l_msg

    const size_t rowbase = (size_t)(Cb + lane) * 64 + half * 32 + chunk * 4;
    float cc4[4], h4[4];
    if (step) {
        float4 cp = *(const float4*)(ccg + rowbase);
        cc4[0] = cp.x; cc4[1] = cp.y; cc4[2] = cp.z; cc4[3] = cp.w;
    } else { cc4[0] = cc4[1] = cc4[2] = cc4[3] = 0.f; }
#pragma unroll
    for (int u4 = 0; u4 < 4; ++u4) cellu(acc + u4 * 4, &cc4[u4], &h4[u4]);

    __syncthreads();
#pragma unroll
    for (int u4 = 0; u4 < 4; ++u4) {
        chT[lane * 33 + chunk * 4 + u4]  = h4[u4];
        bufT[lane * 33 + chunk * 4 + u4] = cc4[u4];
    }
    __syncthreads();
    {
        int row = tid >> 5, cl = tid & 31;
#pragma unroll
        for (int p = 0; p < 4; ++p) {
            int rr = row + p * 16;
            size_t dst = (size_t)(Cb + rr) * 64 + half * 32 + cl;
            ch_cur[dst] = chT[rr * 33 + cl];
            ccg[dst]    = bufT[rr * 33 + cl];
        }
    }
}

// lit: 400 blocks (200 rowgrps x 2 halves)
__global__ __launch_bounds__(512, 4) void lit_step_k(
    const float* __restrict__ out_cur, float* __restrict__ out_nxt,
    const float* __restrict__ chg, float* __restrict__ lcg,
    const int* __restrict__ rowptr, const int* __restrict__ col, const int* __restrict__ cnt,
    const float* __restrict__ wihT, const float* __restrict__ whhT, const float* __restrict__ wflT,
    const float* __restrict__ bfl, const float* __restrict__ Bl,
    const float* __restrict__ Wv, const float* __restrict__ bv, float* __restrict__ vout,
    int step)
{
    __shared__ float bufT[65 * 64 + 1024];   // [k][r] + vote scratch tail
    const int tid = threadIdx.x;
    const int lane = tid & 63;
    const int wv = tid >> 6;
    const int half = blockIdx.x & 1;
    const int Lb = (blockIdx.x >> 1) * 64;
    const int chunk = __builtin_amdgcn_readfirstlane(wv);
    const int hc = half * 8 + chunk;

    for (int i = 0; i < 8; ++i) {
        int srow = wv * 8 + i;
        bufT[lane * 65 + srow] = out_cur[(size_t)(Lb + srow) * 64 + lane];
    }
    __syncthreads();

    const float degf = 1.f + (float)cnt[Lb + lane];
    float acc[16];
#pragma unroll
    for (int u4 = 0; u4 < 4; ++u4)
#pragma unroll
        for (int g = 0; g < 4; ++g) {
            int gc = g * 64 + half * 32 + chunk * 4 + u4;
            acc[u4 * 4 + g] = Bl[gc] + degf * bfl[gc];
        }
    gemmV(bufT, 1, wihT + hc * 1024, acc);           // out[flip] @ wih_top (flip = r^1)
    if (step) gemmV(bufT, 0, whhT + hc * 1024, acc); // lh @ whh
    __syncthreads();   // all gemm reads done before gather overwrites

    for (int i = 0; i < 8; ++i) {
        int srow = wv * 8 + i;
        int l = Lb + srow;
        int e = rowptr[l], eE = rowptr[l + 1];
        float v = bufT[lane * 65 + srow];
        for (; e < eE; e += 8) {
            float t0 = chg[(size_t)col[e    ] * 64 + lane];
            float t1 = chg[(size_t)col[e + 1] * 64 + lane];
            float t2 = chg[(size_t)col[e + 2] * 64 + lane];
            float t3 = chg[(size_t)col[e + 3] * 64 + lane];
            float t4 = chg[(size_t)col[e + 4] * 64 + lane];
            float t5 = chg[(size_t)col[e + 5] * 64 + lane];
            float t6 = chg[(size_t)col[e + 6] * 64 + lane];
            float t7 = chg[(size_t)col[e + 7] * 64 + lane];
            v += ((t0 + t1) + (t2 + t3)) + ((t4 + t5) + (t6 + t7));
        }
        bufT[lane * 65 + srow] = v;
    }
    __syncthreads();
    gemmV(bufT, 0, wflT + hc * 1024, acc);           // folded c_msg

    const size_t rowbase = (size_t)(Lb + lane) * 64 + half * 32 + chunk * 4;
    float lc4[4], h4[4];
    if (step) {
        float4 cp = *(const float4*)(lcg + rowbase);
        lc4[0] = cp.x; lc4[1] = cp.y; lc4[2] = cp.z; lc4[3] = cp.w;
    } else { lc4[0] = lc4[1] = lc4[2] = lc4[3] = 0.f; }
#pragma unroll
    for (int u4 = 0; u4 < 4; ++u4) cellu(acc + u4 * 4, &lc4[u4], &h4[u4]);

    float* hS = bufT;
    float* cS = bufT + 64 * 33;
    __syncthreads();
#pragma unroll
    for (int u4 = 0; u4 < 4; ++u4) {
        hS[lane * 33 + chunk * 4 + u4] = h4[u4];
        cS[lane * 33 + chunk * 4 + u4] = lc4[u4];
    }
    if (step == STEPS_ - 1) {
        float p = 0.f;
#pragma unroll
        for (int u4 = 0; u4 < 4; ++u4)
            p += h4[u4] * Wv[half * 32 + chunk * 4 + u4];
        bufT[64 * 66 + lane * 9 + chunk] = p;
    }
    __syncthreads();
    {
        int row = tid >> 5, cl = tid & 31;
#pragma unroll
        for (int p = 0; p < 4; ++p) {
            int rr = row + p * 16;
            size_t dst = (size_t)(Lb + rr) * 64 + half * 32 + cl;
            out_nxt[dst] = hS[rr * 33 + cl];
            lcg[dst]     = cS[rr * 33 + cl];
        }
    }
    if (step == STEPS_ - 1 && wv == 0) {
        float v = (half == 0) ? bv[0] : 0.f;
#pragma unroll
        for (int q = 0; q < 8; ++q) v += bufT[64 * 66 + lane * 9 + q];
        int R = Lb + lane;
        int b = R / NV2_;
        int pos = R - b * NV2_;
        int pi = (pos >> 1) + (pos & 1) * 400;   // undo pair-interleave
        atomicAdd(vout + b * NPG_ + pi, v);
    }
}

// ---------------- host ----------------

extern "C" void kernel_launch(void* const* d_in, const int* in_sizes, int n_in,
                              void* d_out, int out_size, void* d_ws, size_t ws_size,
                              hipStream_t stream)
{
    (void)in_sizes; (void)n_in; (void)out_size; (void)ws_size;
    const float* x    = (const float*)d_in[0];
    const int*   ei   = (const int*)d_in[2];
    const float* liw  = (const float*)d_in[4];
    const float* lib  = (const float*)d_in[5];
    const float* ciw  = (const float*)d_in[6];
    const float* cib  = (const float*)d_in[7];
    const float* lm1  = (const float*)d_in[8];
    const float* lm1b = (const float*)d_in[9];
    const float* lm2  = (const float*)d_in[10];
    const float* lm2b = (const float*)d_in[11];
    const float* lm3  = (const float*)d_in[12];
    const float* lm3b = (const float*)d_in[13];
    const float* cm1  = (const float*)d_in[14];
    const float* cm1b = (const float*)d_in[15];
    const float* cm2  = (const float*)d_in[16];
    const float* cm2b = (const float*)d_in[17];
    const float* cm3  = (const float*)d_in[18];
    const float* cm3b = (const float*)d_in[19];
    const float* lu_wih = (const float*)d_in[20];
    const float* lu_whh = (const float*)d_in[21];
    const float* lu_bih = (const float*)d_in[22];
    const float* lu_bhh = (const float*)d_in[23];
    const float* cu_wih = (const float*)d_in[24];
    const float* cu_whh = (const float*)d_in[25];
    const float* cu_bih = (const float*)d_in[26];
    const float* cu_bhh = (const float*)d_in[27];
    const float* lv1  = (const float*)d_in[28];
    const float* lv1b = (const float*)d_in[29];
    const float* lv2  = (const float*)d_in[30];
    const float* lv2b = (const float*)d_in[31];
    const float* lv3  = (const float*)d_in[32];
    const float* lv3b = (const float*)d_in[33];

    float* F = (float*)d_ws;
    size_t o = 0;
    auto A = [&](size_t n) { float* p = F + o; o += n; return p; };
    float* outA  = A((size_t)NLIT_ * 64);
    float* outB  = A((size_t)NLIT_ * 64);
    float* outc0 = A((size_t)NCLS_ * 64);
    float* chA   = A((size_t)(NCLS_ + 1) * 64);
    float* chB   = A((size_t)(NCLS_ + 1) * 64);
    float* ccg   = A((size_t)NCLS_ * 64);
    float* lcg   = A((size_t)NLIT_ * 64);
    float* Wl    = A(4096);
    float* Wc    = A(4096);
    float* bl    = A(64);
    float* bc    = A(64);
    float* Wv    = A(64);
    float* bv    = A(16);
    float* Wfl   = A(64 * 256);
    float* bfl   = A(256);
    float* Bl    = A(256);
    float* Wfc   = A(64 * 256);
    float* Bc    = A(256);
    float* Tbuf  = A(2 * 4096);
    float* ubuf  = A(2 * 64);
    float* wihT  = A(16384);
    float* whhT  = A(16384);
    float* wflT  = A(16384);
    float* cwhhT = A(16384);
    float* wfcT  = A(16384);
    int* I = (int*)(F + o);
    int* llits  = I; I += NE_;
    int* rowptr = I; I += 12804;
    int* cursor = I; I += NLIT_;
    int* pcol   = I; I += 184320;
    int* cnt    = I; I += NLIT_;

    hipMemsetAsync(cnt, 0, NLIT_ * sizeof(int), stream);
    hipMemsetAsync(d_out, 0, (size_t)NN_ * sizeof(float), stream);

    collapseT_k<<<128, 64, 0, stream>>>(lm1, lm1b, lm2, lm2b, cm1, cm1b, cm2, cm2b, Tbuf, ubuf);
    collapseW_k<<<129, 64, 0, stream>>>(lm3, lm3b, cm3, cm3b, Tbuf, ubuf, Wl, bl, Wc, bc,
                                        lv1, lv1b, lv2, lv2b, lv3, lv3b, Wv, bv);
    fold2_k<<<128, 256, 0, stream>>>(Wl, bl, Wc, bc,
                                     lu_wih, lu_bih, lu_bhh,
                                     cu_wih, cu_bih, cu_bhh,
                                     Wfl, bfl, Bl, Wfc, Bc);
    WT5 wt;
    wt.src[0] = lu_wih; wt.dst[0] = wihT;
    wt.src[1] = lu_whh; wt.dst[1] = whhT;
    wt.src[2] = Wfl;    wt.dst[2] = wflT;
    wt.src[3] = cu_whh; wt.dst[3] = cwhhT;
    wt.src[4] = Wfc;    wt.dst[4] = wfcT;
    wtransAll_k<<<80, 1024, 0, stream>>>(wt);
    init_k<<<(NN_ * 64 + 255) / 256, 256, 0, stream>>>(x, liw, lib, ciw, cib,
                                                       outA, outc0, chA, chB);
    econv_k<<<NE_ / 256, 256, 0, stream>>>(ei, llits, cnt);
    scan_k<<<1, 1024, 0, stream>>>(cnt, rowptr, cursor);
    fill_k<<<NE_ / 256, 256, 0, stream>>>(llits, cursor, pcol);
    pad_k<<<(NLIT_ + 255) / 256, 256, 0, stream>>>(cnt, rowptr, pcol);

    for (int s = 0; s < STEPS_; ++s) {
        const float* oc  = (s & 1) ? outB : outA;
        float*       on  = (s & 1) ? outA : outB;
        float*       chc = (s & 1) ? chA : chB;
        const float* chp = (s & 1) ? chB : chA;
        clause_step_k<<<220, 512, 0, stream>>>(oc, outc0, chc, chp, ccg,
                                               llits, wfcT, cwhhT, Bc, s);
        lit_step_k<<<400, 512, 0, stream>>>(oc, on, chc, lcg, rowptr, pcol, cnt,
                                            wihT, whhT, wflT, bfl, Bl,
                                            Wv, bv, (float*)d_out, s);
    }
}